// Round 1
// baseline (1593.221 us; speedup 1.0000x reference)
//
#include <hip/hip_runtime.h>
#include <stdint.h>

#define BB 64
#define LL 512
#define EMB 768
#define DM 32
#define NH 4
#define DH 8
#define NCODES 8192
#define NCQ 16
#define NROWS 1024    // BB*NCQ
#define TOT 32768     // BB*LL

// workspace offsets (in floats)
#define OFF_LOGITS 0ll
#define OFF_X      8388608ll
#define OFF_QKV    9437184ll
#define OFF_ATTN   12582912ll
#define OFF_FLAT   13631488ll
#define OFF_FSQ    14417920ll
#define OFF_CSQ    14418944ll

// ---------------- Threefry2x32, key = (0, 42)  (jax.random.key(42)) ----------------
__device__ __forceinline__ uint32_t rotl32(uint32_t x, int r) { return (x << r) | (x >> (32 - r)); }

__device__ __forceinline__ void tf2x32_key42(uint32_t x0, uint32_t x1, uint32_t& o0, uint32_t& o1) {
  const uint32_t k0 = 0u, k1 = 42u;
  const uint32_t k2 = k0 ^ k1 ^ 0x1BD11BDAu;
  x0 += k0; x1 += k1;
  x0 += x1; x1 = rotl32(x1,13); x1 ^= x0;
  x0 += x1; x1 = rotl32(x1,15); x1 ^= x0;
  x0 += x1; x1 = rotl32(x1,26); x1 ^= x0;
  x0 += x1; x1 = rotl32(x1, 6); x1 ^= x0;
  x0 += k1; x1 += k2 + 1u;
  x0 += x1; x1 = rotl32(x1,17); x1 ^= x0;
  x0 += x1; x1 = rotl32(x1,29); x1 ^= x0;
  x0 += x1; x1 = rotl32(x1,16); x1 ^= x0;
  x0 += x1; x1 = rotl32(x1,24); x1 ^= x0;
  x0 += k2; x1 += k0 + 2u;
  x0 += x1; x1 = rotl32(x1,13); x1 ^= x0;
  x0 += x1; x1 = rotl32(x1,15); x1 ^= x0;
  x0 += x1; x1 = rotl32(x1,26); x1 ^= x0;
  x0 += x1; x1 = rotl32(x1, 6); x1 ^= x0;
  x0 += k0; x1 += k1 + 3u;
  x0 += x1; x1 = rotl32(x1,17); x1 ^= x0;
  x0 += x1; x1 = rotl32(x1,29); x1 ^= x0;
  x0 += x1; x1 = rotl32(x1,16); x1 ^= x0;
  x0 += x1; x1 = rotl32(x1,24); x1 ^= x0;
  x0 += k1; x1 += k2 + 4u;
  x0 += x1; x1 = rotl32(x1,13); x1 ^= x0;
  x0 += x1; x1 = rotl32(x1,15); x1 ^= x0;
  x0 += x1; x1 = rotl32(x1,26); x1 ^= x0;
  x0 += x1; x1 = rotl32(x1, 6); x1 ^= x0;
  x0 += k2; x1 += k0 + 5u;
  o0 = x0; o1 = x1;
}

// JAX partitionable threefry 32-bit random bits for flat index idx (< 2^32 here):
// counters (hi,lo) = (0, idx); bits = y0 ^ y1.
__device__ __forceinline__ float gumbel_at(uint32_t idx) {
  uint32_t y0, y1;
  tf2x32_key42(0u, idx, y0, y1);
  uint32_t bits = y0 ^ y1;
  float f = __uint_as_float((bits >> 9) | 0x3f800000u) - 1.0f;   // [0,1), 23 mantissa bits
  float u = fmaxf(f, 1.17549435e-38f);                           // jax uniform(minval=tiny)
  return -logf(-logf(u));
}

// ---------------- LN over 32 lanes (cols) within a 32-lane half-wave ----------------
__device__ __forceinline__ float ln32(float v, float g, float b) {
  float mu = v;
  #pragma unroll
  for (int off = 16; off >= 1; off >>= 1) mu += __shfl_xor(mu, off);
  mu *= 0.03125f;
  float d = v - mu;
  float vv = d * d;
  #pragma unroll
  for (int off = 16; off >= 1; off >>= 1) vv += __shfl_xor(vv, off);
  vv *= 0.03125f;
  return g * d / sqrtf(vv + 1e-5f) + b;
}

// ---------------- K0: x = xcq @ fc_in_w.T + b ; also copy xcq -> out (output 1) ------
__global__ __launch_bounds__(256) void k_fcin(const float* __restrict__ xcq,
                                              const float* __restrict__ W,
                                              const float* __restrict__ b,
                                              float* __restrict__ x,
                                              float* __restrict__ outcopy) {
  __shared__ __align__(16) float xs[8 * 768];
  int t = threadIdx.x;
  long base4 = (long)blockIdx.x * 1536;   // float4 units (8*768/4)
  const float4* src4 = (const float4*)xcq;
  float4* dst4 = (float4*)outcopy;
  float4* xs4 = (float4*)xs;
  #pragma unroll
  for (int i = 0; i < 6; i++) {
    int f = t + 256 * i;
    float4 v = src4[base4 + f];
    xs4[f] = v;
    dst4[base4 + f] = v;
  }
  __syncthreads();
  int row = t >> 5, col = t & 31;
  const float* wr = W + col * 768;
  const float* xr = xs + row * 768;
  float acc = 0.f;
  for (int j = 0; j < 768; j += 4) {
    float4 w4 = *(const float4*)(wr + j);
    float4 x4 = *(const float4*)(xr + j);
    acc += x4.x * w4.x + x4.y * w4.y + x4.z * w4.z + x4.w * w4.w;
  }
  x[(long)blockIdx.x * 256 + t] = acc + b[col];
}

// ---------------- K1: qkv = x @ Win.T + bin  (per layer) ----------------
__global__ __launch_bounds__(256) void k_qkv(const float* __restrict__ x,
                                             const float* __restrict__ W,
                                             const float* __restrict__ b,
                                             float* __restrict__ qkv) {
  __shared__ float xs[8 * 32];
  int t = threadIdx.x;
  long rbase = (long)blockIdx.x * 8;
  xs[t] = x[rbase * 32 + t];
  __syncthreads();
  #pragma unroll
  for (int i = 0; i < 3; i++) {
    int f = t + 256 * i;            // f = row*96 + col
    int row = f / 96, col = f - row * 96;
    const float* wr = W + col * 32;
    const float* xr = xs + row * 32;
    float acc = 0.f;
    for (int j = 0; j < 32; j += 4) {
      float4 w4 = *(const float4*)(wr + j);
      float4 x4 = *(const float4*)(xr + j);
      acc += x4.x * w4.x + x4.y * w4.y + x4.z * w4.z + x4.w * w4.w;
    }
    qkv[rbase * 96 + f] = acc + b[col];
  }
}

// ---------------- K2: attention for one (batch, head, half-of-queries) ----------------
__global__ __launch_bounds__(256) void k_attn(const float* __restrict__ qkv,
                                              const int* __restrict__ amask,
                                              float* __restrict__ attno) {
  int z = blockIdx.x;               // 512 blocks
  int b = z >> 3;
  int h = (z >> 1) & 3;
  int half = z & 1;
  __shared__ float ks_[512 * 8];
  __shared__ float vs[512 * 8];
  __shared__ float inval[512];      // 1.0 if masked-out
  int t = threadIdx.x;
  long qbase = (long)b * 512 * 96;
  for (int i = 0; i < 16; i++) {
    int f = t + 256 * i;            // l*8+d
    int l = f >> 3, d = f & 7;
    ks_[f] = qkv[qbase + (long)l * 96 + 32 + h * 8 + d];
    vs[f]  = qkv[qbase + (long)l * 96 + 64 + h * 8 + d];
  }
  for (int i = 0; i < 2; i++) {
    int l = t + 256 * i;
    inval[l] = (l < 16 || amask[b * 496 + (l - 16)] != 0) ? 0.f : 1.f;
  }
  __syncthreads();
  const float scale = 0.35355339059327373f;  // 1/sqrt(8)
  int lq = half * 256 + t;
  float q[8];
  #pragma unroll
  for (int d = 0; d < 8; d++) q[d] = qkv[qbase + (long)lq * 96 + h * 8 + d];
  // pass 1: row max (matches jax.nn.softmax max over all keys incl. -1e9)
  float m = -3.4e38f;
  for (int lk = 0; lk < 512; lk++) {
    float s = 0.f;
    #pragma unroll
    for (int d = 0; d < 8; d++) s += q[d] * ks_[lk * 8 + d];
    s *= scale;
    s = inval[lk] != 0.f ? -1e9f : s;
    m = fmaxf(m, s);
  }
  // pass 2: exp, denom, o accumulate
  float denom = 0.f;
  float o[8] = {0, 0, 0, 0, 0, 0, 0, 0};
  for (int lk = 0; lk < 512; lk++) {
    float s = 0.f;
    #pragma unroll
    for (int d = 0; d < 8; d++) s += q[d] * ks_[lk * 8 + d];
    s *= scale;
    s = inval[lk] != 0.f ? -1e9f : s;
    float p = expf(s - m);
    denom += p;
    #pragma unroll
    for (int d = 0; d < 8; d++) o[d] += p * vs[lk * 8 + d];
  }
  float inv = 1.f / denom;
  #pragma unroll
  for (int d = 0; d < 8; d++)
    attno[((long)b * 512 + lq) * 32 + h * 8 + d] = o[d] * inv;
}

// ---------------- K3: x = LN1(x + attno @ Wout.T + bout) ----------------
__global__ __launch_bounds__(256) void k_oproj_ln(const float* __restrict__ attno,
                                                  const float* __restrict__ W,
                                                  const float* __restrict__ b,
                                                  const float* __restrict__ g,
                                                  const float* __restrict__ beta,
                                                  float* __restrict__ x) {
  __shared__ float os[8 * 32];
  int t = threadIdx.x;
  long rbase = (long)blockIdx.x * 8;
  os[t] = attno[rbase * 32 + t];
  __syncthreads();
  int row = t >> 5, col = t & 31;
  const float* wr = W + col * 32;
  const float* orow = os + row * 32;
  float acc = 0.f;
  for (int j = 0; j < 32; j++) acc += orow[j] * wr[j];
  float v = acc + b[col] + x[rbase * 32 + t];
  x[rbase * 32 + t] = ln32(v, g[col], beta[col]);
}

// ---------------- K4: x = LN2(x + relu(x@W1.T+b1)@W2.T + b2) ----------------
__global__ __launch_bounds__(256) void k_ffn_ln(const float* __restrict__ x,
                                                const float* __restrict__ W1,
                                                const float* __restrict__ b1,
                                                const float* __restrict__ W2,
                                                const float* __restrict__ b2,
                                                const float* __restrict__ g,
                                                const float* __restrict__ beta,
                                                float* __restrict__ xout) {
  __shared__ float xs[8 * 32];
  __shared__ float hs[8 * 64];
  int t = threadIdx.x;
  long rbase = (long)blockIdx.x * 8;
  xs[t] = x[rbase * 32 + t];
  __syncthreads();
  #pragma unroll
  for (int i = 0; i < 2; i++) {
    int f = t + 256 * i;           // row*64+col
    int row = f >> 6, col = f & 63;
    const float* wr = W1 + col * 32;
    const float* xr = xs + row * 32;
    float acc = 0.f;
    for (int j = 0; j < 32; j++) acc += xr[j] * wr[j];
    hs[f] = fmaxf(acc + b1[col], 0.f);
  }
  __syncthreads();
  int row = t >> 5, col = t & 31;
  const float* wr = W2 + col * 64;
  const float* hr = hs + row * 64;
  float acc = 0.f;
  for (int j = 0; j < 64; j++) acc += hr[j] * wr[j];
  float v = acc + b2[col] + xs[t];
  xout[rbase * 32 + t] = ln32(v, g[col], beta[col]);
}

// ---------------- K5: flat = x[:, :16] @ fc_out_w.T + b ; flat_sq ----------------
__global__ __launch_bounds__(256) void k_fcout(const float* __restrict__ x,
                                               const float* __restrict__ W,
                                               const float* __restrict__ b,
                                               float* __restrict__ flat,
                                               float* __restrict__ flat_sq) {
  int n = blockIdx.x;
  int src = (n >> 4) * 512 + (n & 15);
  __shared__ float xs[32];
  __shared__ float red[4];
  int t = threadIdx.x;
  if (t < 32) xs[t] = x[(long)src * 32 + t];
  __syncthreads();
  float ss = 0.f;
  #pragma unroll
  for (int i = 0; i < 3; i++) {
    int e = t + 256 * i;
    const float* wr = W + e * 32;
    float acc = 0.f;
    for (int j = 0; j < 32; j++) acc += xs[j] * wr[j];
    acc += b[e];
    flat[(long)n * 768 + e] = acc;
    ss += acc * acc;
  }
  #pragma unroll
  for (int off = 32; off >= 1; off >>= 1) ss += __shfl_xor(ss, off);
  if ((t & 63) == 0) red[t >> 6] = ss;
  __syncthreads();
  if (t == 0) flat_sq[n] = (red[0] + red[1]) + (red[2] + red[3]);
}

// ---------------- K6: cb_sq[k] = sum(codebook[k]^2) ----------------
__global__ __launch_bounds__(256) void k_cbsq(const float* __restrict__ cb,
                                              float* __restrict__ cb_sq) {
  int w = threadIdx.x >> 6, lane = threadIdx.x & 63;
  int k = blockIdx.x * 4 + w;
  const float* row = cb + (long)k * 768;
  float s = 0.f;
  #pragma unroll
  for (int i = 0; i < 12; i++) { float v = row[lane + 64 * i]; s += v * v; }
  #pragma unroll
  for (int off = 32; off >= 1; off >>= 1) s += __shfl_xor(s, off);
  if (lane == 0) cb_sq[k] = s;
}

// ---------------- K7: logits[n,k] = -(fsq[n] + csq[k] - 2 flat.cb) - 1e-5 ----------
__global__ __launch_bounds__(256) void k_logits(const float* __restrict__ flat,
                                                const float* __restrict__ cb,
                                                const float* __restrict__ flat_sq,
                                                const float* __restrict__ cb_sq,
                                                float* __restrict__ logits) {
  int rb = blockIdx.x >> 5;     // 128 row-blocks of 8
  int cblk = blockIdx.x & 31;   // 32 col-blocks of 256
  __shared__ __align__(16) float fs[8 * 768];     // 24 KB
  __shared__ __align__(16) float cs[256 * 36];    // 36 KB, stride 36 kills b128 conflicts
  int t = threadIdx.x;
  long frbase = (long)rb * 8 * 768;
  float4* fs4 = (float4*)fs;
  const float4* flat4 = (const float4*)(flat + frbase);
  #pragma unroll
  for (int i = 0; i < 6; i++) fs4[t + 256 * i] = flat4[t + 256 * i];
  float4 acc[8];
  #pragma unroll
  for (int r = 0; r < 8; r++) acc[r] = make_float4(0.f, 0.f, 0.f, 0.f);
  const long cbase = (long)cblk * 256 * 768;
  int lcol = t >> 3;                    // 0..31 within-wave col group base
  int lkk = (t & 7) * 4;
  for (int kc = 0; kc < 768; kc += 32) {
    __syncthreads();
    #pragma unroll
    for (int i = 0; i < 8; i++) {
      int col = lcol + 32 * i;
      float4 v = *(const float4*)(cb + cbase + (long)col * 768 + kc + lkk);
      *(float4*)(cs + col * 36 + lkk) = v;
    }
    __syncthreads();
    const float* csr = cs + t * 36;
    #pragma unroll
    for (int k = 0; k < 32; k += 4) {
      float4 c4 = *(const float4*)(csr + k);
      #pragma unroll
      for (int r = 0; r < 8; r++) {
        float4 f4 = *(const float4*)(fs + r * 768 + kc + k);
        acc[r].x = fmaf(f4.x, c4.x, acc[r].x);
        acc[r].y = fmaf(f4.y, c4.y, acc[r].y);
        acc[r].z = fmaf(f4.z, c4.z, acc[r].z);
        acc[r].w = fmaf(f4.w, c4.w, acc[r].w);
      }
    }
  }
  int col = cblk * 256 + t;
  float csq = cb_sq[col];
  #pragma unroll
  for (int r = 0; r < 8; r++) {
    int n = rb * 8 + r;
    float dot = (acc[r].x + acc[r].y) + (acc[r].z + acc[r].w);
    float dist = flat_sq[n] + csq - 2.f * dot;
    logits[(long)n * 8192 + col] = -dist - 1e-5f;
  }
}

// ---------------- K8: 16 gumbel-max draws per row -> xq -> output 0 ----------------
// gumbel range is [-4.4697, 15.9425]; only codes with logit >= rowmax - 20.5 can win.
__global__ __launch_bounds__(256) void k_sample(const float* __restrict__ logits,
                                                const float* __restrict__ cb,
                                                const float* __restrict__ flat,
                                                float* __restrict__ out0) {
  int n = blockIdx.x, t = threadIdx.x;
  const float* lrow = logits + (long)n * 8192;
  __shared__ float s_max[4];
  __shared__ int s_cnt;
  __shared__ int cand[8192];
  __shared__ float redv[64];
  __shared__ int redi[64];
  __shared__ int draws[16];
  // pass 1: row max
  float m = -3.4e38f;
  for (int i = 0; i < 32; i++) m = fmaxf(m, lrow[t + 256 * i]);
  #pragma unroll
  for (int off = 32; off >= 1; off >>= 1) m = fmaxf(m, __shfl_xor(m, off));
  if ((t & 63) == 0) s_max[t >> 6] = m;
  if (t == 0) s_cnt = 0;
  __syncthreads();
  float rowmax = fmaxf(fmaxf(s_max[0], s_max[1]), fmaxf(s_max[2], s_max[3]));
  float thresh = rowmax - 20.5f;
  for (int i = 0; i < 32; i++) {
    int k = t + 256 * i;
    if (lrow[k] >= thresh) { int p = atomicAdd(&s_cnt, 1); cand[p] = k; }
  }
  __syncthreads();
  int ncand = s_cnt;
  float bv[16]; int bi[16];
  #pragma unroll
  for (int s = 0; s < 16; s++) { bv[s] = -3.4e38f; bi[s] = 0x7fffffff; }
  for (int c = t; c < ncand; c += 256) {
    int k = cand[c];
    float lg = lrow[k];
    #pragma unroll
    for (int s = 0; s < 16; s++) {
      uint32_t idx = ((uint32_t)((s << 10) + n) << 13) | (uint32_t)k;  // flat (s,n,k) index
      float val = gumbel_at(idx) + lg;
      if (val > bv[s] || (val == bv[s] && k < bi[s])) { bv[s] = val; bi[s] = k; }
    }
  }
  #pragma unroll
  for (int s = 0; s < 16; s++) {
    #pragma unroll
    for (int off = 32; off >= 1; off >>= 1) {
      float ov = __shfl_xor(bv[s], off);
      int oi = __shfl_xor(bi[s], off);
      if (ov > bv[s] || (ov == bv[s] && oi < bi[s])) { bv[s] = ov; bi[s] = oi; }
    }
    if ((t & 63) == 0) { redv[s * 4 + (t >> 6)] = bv[s]; redi[s * 4 + (t >> 6)] = bi[s]; }
  }
  __syncthreads();
  if (t < 16) {
    float bvv = redv[t * 4]; int bii = redi[t * 4];
    #pragma unroll
    for (int w = 1; w < 4; w++) {
      float ov = redv[t * 4 + w]; int oi = redi[t * 4 + w];
      if (ov > bvv || (ov == bvv && oi < bii)) { bvv = ov; bii = oi; }
    }
    draws[t] = bii;
  }
  __syncthreads();
  #pragma unroll
  for (int i = 0; i < 3; i++) {
    int e = t + 256 * i;
    float ssum = 0.f;
    #pragma unroll
    for (int s = 0; s < 16; s++) ssum += cb[(long)draws[s] * 768 + e];
    float xq = ssum * 0.0625f;
    float fl = flat[(long)n * 768 + e];
    out0[(long)n * 768 + e] = fl + (xq - fl);   // mimic straight-through add/sub
  }
}

extern "C" void kernel_launch(void* const* d_in, const int* in_sizes, int n_in,
                              void* d_out, int out_size, void* d_ws, size_t ws_size,
                              hipStream_t stream) {
  (void)in_sizes; (void)n_in; (void)out_size; (void)ws_size;
  const float* xcq      = (const float*)d_in[0];
  const int*   amask    = (const int*)d_in[1];
  const float* fc_in_w  = (const float*)d_in[2];
  const float* fc_in_b  = (const float*)d_in[3];
  const float* fc_out_w = (const float*)d_in[4];
  const float* fc_out_b = (const float*)d_in[5];
  const float* enc_in_w = (const float*)d_in[6];
  const float* enc_in_b = (const float*)d_in[7];
  const float* enc_out_w= (const float*)d_in[8];
  const float* enc_out_b= (const float*)d_in[9];
  const float* ff1w     = (const float*)d_in[10];
  const float* ff1b     = (const float*)d_in[11];
  const float* ff2w     = (const float*)d_in[12];
  const float* ff2b     = (const float*)d_in[13];
  const float* ln1g     = (const float*)d_in[14];
  const float* ln1b     = (const float*)d_in[15];
  const float* ln2g     = (const float*)d_in[16];
  const float* ln2b     = (const float*)d_in[17];
  const float* cb       = (const float*)d_in[18];
  float* out = (float*)d_out;
  float* ws  = (float*)d_ws;

  float* x      = ws + OFF_X;
  float* qkv    = ws + OFF_QKV;
  float* attno  = ws + OFF_ATTN;
  float* flat   = ws + OFF_FLAT;
  float* fsq    = ws + OFF_FSQ;
  float* csq    = ws + OFF_CSQ;
  float* logits = ws + OFF_LOGITS;

  k_fcin<<<4096, 256, 0, stream>>>(xcq, fc_in_w, fc_in_b, x, out + 786432);
  for (int l = 0; l < 2; l++) {
    k_qkv<<<4096, 256, 0, stream>>>(x, enc_in_w + l * 96 * 32, enc_in_b + l * 96, qkv);
    k_attn<<<512, 256, 0, stream>>>(qkv, amask, attno);
    k_oproj_ln<<<4096, 256, 0, stream>>>(attno, enc_out_w + l * 32 * 32, enc_out_b + l * 32,
                                         ln1g + l * 32, ln1b + l * 32, x);
    k_ffn_ln<<<4096, 256, 0, stream>>>(x, ff1w + l * 64 * 32, ff1b + l * 64,
                                       ff2w + l * 32 * 64, ff2b + l * 32,
                                       ln2g + l * 32, ln2b + l * 32, x);
  }
  k_fcout<<<1024, 256, 0, stream>>>(x, fc_out_w, fc_out_b, flat, fsq);
  k_cbsq<<<2048, 256, 0, stream>>>(cb, csq);
  k_logits<<<4096, 256, 0, stream>>>(flat, cb, fsq, csq, logits);
  k_sample<<<1024, 256, 0, stream>>>(logits, cb, flat, out);
}

// Round 2
// 1110.169 us; speedup vs baseline: 1.4351x; 1.4351x over previous
//
#include <hip/hip_runtime.h>
#include <stdint.h>

#define NCODES 8192
#define NROWS 1024    // B*NCQ

// workspace offsets (in floats)
#define OFF_LOGITS 0ll
#define OFF_X      8388608ll
#define OFF_QKV    9437184ll
#define OFF_ATTN   12582912ll
#define OFF_FLAT   13631488ll
#define OFF_CSQ    14418944ll

// ---------------- Threefry2x32, key = (0, 42)  (jax.random.key(42)) ----------------
__device__ __forceinline__ uint32_t rotl32(uint32_t x, int r) { return (x << r) | (x >> (32 - r)); }

__device__ __forceinline__ void tf2x32_key42(uint32_t x0, uint32_t x1, uint32_t& o0, uint32_t& o1) {
  const uint32_t k0 = 0u, k1 = 42u;
  const uint32_t k2 = k0 ^ k1 ^ 0x1BD11BDAu;
  x0 += k0; x1 += k1;
  x0 += x1; x1 = rotl32(x1,13); x1 ^= x0;
  x0 += x1; x1 = rotl32(x1,15); x1 ^= x0;
  x0 += x1; x1 = rotl32(x1,26); x1 ^= x0;
  x0 += x1; x1 = rotl32(x1, 6); x1 ^= x0;
  x0 += k1; x1 += k2 + 1u;
  x0 += x1; x1 = rotl32(x1,17); x1 ^= x0;
  x0 += x1; x1 = rotl32(x1,29); x1 ^= x0;
  x0 += x1; x1 = rotl32(x1,16); x1 ^= x0;
  x0 += x1; x1 = rotl32(x1,24); x1 ^= x0;
  x0 += k2; x1 += k0 + 2u;
  x0 += x1; x1 = rotl32(x1,13); x1 ^= x0;
  x0 += x1; x1 = rotl32(x1,15); x1 ^= x0;
  x0 += x1; x1 = rotl32(x1,26); x1 ^= x0;
  x0 += x1; x1 = rotl32(x1, 6); x1 ^= x0;
  x0 += k0; x1 += k1 + 3u;
  x0 += x1; x1 = rotl32(x1,17); x1 ^= x0;
  x0 += x1; x1 = rotl32(x1,29); x1 ^= x0;
  x0 += x1; x1 = rotl32(x1,16); x1 ^= x0;
  x0 += x1; x1 = rotl32(x1,24); x1 ^= x0;
  x0 += k1; x1 += k2 + 4u;
  x0 += x1; x1 = rotl32(x1,13); x1 ^= x0;
  x0 += x1; x1 = rotl32(x1,15); x1 ^= x0;
  x0 += x1; x1 = rotl32(x1,26); x1 ^= x0;
  x0 += x1; x1 = rotl32(x1, 6); x1 ^= x0;
  x0 += k2; x1 += k0 + 5u;
  o0 = x0; o1 = x1;
}

__device__ __forceinline__ float gumbel_at(uint32_t idx) {
  uint32_t y0, y1;
  tf2x32_key42(0u, idx, y0, y1);
  uint32_t bits = y0 ^ y1;
  float f = __uint_as_float((bits >> 9) | 0x3f800000u) - 1.0f;
  float u = fmaxf(f, 1.17549435e-38f);
  return -logf(-logf(u));
}

// ---------------- K0: x = xcq @ fc_in_w.T + b ; also copy xcq -> out (output 1) ------
// Block: 64 tokens, 4 waves; wave w computes cols 8w..8w+8 for all 64 tokens.
// W indices are wave-uniform -> scalar loads. X staged per 32-k chunk in LDS.
__global__ __launch_bounds__(256) void k_fcin(const float* __restrict__ xcq,
                                              const float* __restrict__ W,
                                              const float* __restrict__ b,
                                              float* __restrict__ x,
                                              float* __restrict__ outcopy) {
  __shared__ float xs[64 * 36];
  int t = threadIdx.x;
  int w = t >> 6, lane = t & 63;
  long tb = (long)blockIdx.x * 64;
  const float4* xcq4 = (const float4*)xcq;
  float4* out4 = (float4*)outcopy;
  const float4* W4 = (const float4*)W;
  float acc[8];
  #pragma unroll
  for (int i = 0; i < 8; i++) acc[i] = 0.f;

  for (int jc4 = 0; jc4 < 192; jc4 += 8) {   // 24 chunks of 32 floats (8 f4)
    __syncthreads();
    #pragma unroll
    for (int p = 0; p < 2; p++) {
      int f = t + 256 * p;
      int row = f >> 3, j4 = f & 7;
      long g = (tb + row) * 192 + jc4 + j4;
      float4 v = xcq4[g];
      *(float4*)(xs + row * 36 + j4 * 4) = v;
      out4[g] = v;
    }
    __syncthreads();
    #pragma unroll
    for (int j4 = 0; j4 < 8; j4++) {
      float4 xv = *(const float4*)(xs + lane * 36 + j4 * 4);
      #pragma unroll
      for (int ci = 0; ci < 8; ci++) {
        int c = w * 8 + ci;
        float4 wv = W4[c * 192 + jc4 + j4];   // wave-uniform -> s_load
        acc[ci] += xv.x * wv.x + xv.y * wv.y + xv.z * wv.z + xv.w * wv.w;
      }
    }
  }
  __syncthreads();
  // transpose through LDS for coalesced x write
  *(float4*)(xs + lane * 36 + w * 8)     = make_float4(acc[0] + b[w*8+0], acc[1] + b[w*8+1], acc[2] + b[w*8+2], acc[3] + b[w*8+3]);
  *(float4*)(xs + lane * 36 + w * 8 + 4) = make_float4(acc[4] + b[w*8+4], acc[5] + b[w*8+5], acc[6] + b[w*8+6], acc[7] + b[w*8+7]);
  __syncthreads();
  float4* x4 = (float4*)x;
  #pragma unroll
  for (int p = 0; p < 2; p++) {
    int f = t + 256 * p;
    int row = f >> 3, c4 = f & 7;
    x4[(tb + row) * 8 + c4] = *(const float4*)(xs + row * 36 + c4 * 4);
  }
}

// ---------------- K1: qkv = x @ Win.T + bin  (per-token, W wave-uniform) ----------------
__global__ __launch_bounds__(64) void k_qkv(const float* __restrict__ x,
                                            const float* __restrict__ W,
                                            const float* __restrict__ b,
                                            float* __restrict__ qkv) {
  long token = (long)blockIdx.x * 64 + threadIdx.x;
  const float4* x4 = (const float4*)x;
  const float4* W4 = (const float4*)W;
  float4* q4 = (float4*)qkv;
  float4 xr[8];
  #pragma unroll
  for (int j4 = 0; j4 < 8; j4++) xr[j4] = x4[token * 8 + j4];
  #pragma unroll
  for (int c4 = 0; c4 < 24; c4++) {
    float s[4];
    #pragma unroll
    for (int q = 0; q < 4; q++) {
      int c = c4 * 4 + q;
      float acc = 0.f;
      #pragma unroll
      for (int j4 = 0; j4 < 8; j4++) {
        float4 wv = W4[c * 8 + j4];   // uniform
        acc += xr[j4].x * wv.x + xr[j4].y * wv.y + xr[j4].z * wv.z + xr[j4].w * wv.w;
      }
      s[q] = acc + b[c];
    }
    q4[token * 24 + c4] = make_float4(s[0], s[1], s[2], s[3]);
  }
}

// ---------------- K2: attention, (batch, head, half-of-queries) per block ----------------
__global__ __launch_bounds__(256) void k_attn(const float* __restrict__ qkv,
                                              const int* __restrict__ amask,
                                              float* __restrict__ attno) {
  int z = blockIdx.x;
  int b = z >> 3;
  int h = (z >> 1) & 3;
  int half = z & 1;
  __shared__ float4 ks4[512 * 2];
  __shared__ float4 vs4[512 * 2];
  __shared__ float inval[512];
  int t = threadIdx.x;
  long qb4 = (long)b * 512 * 24;
  const float4* qkv4 = (const float4*)qkv;
  #pragma unroll
  for (int p = 0; p < 4; p++) {
    int f = t + 256 * p;             // token*2 + half4
    int tok = f >> 1, hf = f & 1;
    ks4[f] = qkv4[qb4 + (long)tok * 24 + 8 + h * 2 + hf];
    vs4[f] = qkv4[qb4 + (long)tok * 24 + 16 + h * 2 + hf];
  }
  #pragma unroll
  for (int p = 0; p < 2; p++) {
    int l = t + 256 * p;
    inval[l] = (l < 16 || amask[b * 496 + (l - 16)] != 0) ? 0.f : 1.f;
  }
  __syncthreads();
  const float scale = 0.35355339059327373f;
  int lq = half * 256 + t;
  float4 qa = qkv4[qb4 + (long)lq * 24 + h * 2];
  float4 qb = qkv4[qb4 + (long)lq * 24 + h * 2 + 1];
  float m = -3.4e38f;
  for (int lk = 0; lk < 512; lk++) {
    float4 ka = ks4[lk * 2], kb = ks4[lk * 2 + 1];
    float s = qa.x*ka.x + qa.y*ka.y + qa.z*ka.z + qa.w*ka.w
            + qb.x*kb.x + qb.y*kb.y + qb.z*kb.z + qb.w*kb.w;
    s *= scale;
    s = inval[lk] != 0.f ? -1e9f : s;
    m = fmaxf(m, s);
  }
  float denom = 0.f;
  float4 o0 = make_float4(0,0,0,0), o1 = make_float4(0,0,0,0);
  for (int lk = 0; lk < 512; lk++) {
    float4 ka = ks4[lk * 2], kb = ks4[lk * 2 + 1];
    float s = qa.x*ka.x + qa.y*ka.y + qa.z*ka.z + qa.w*ka.w
            + qb.x*kb.x + qb.y*kb.y + qb.z*kb.z + qb.w*kb.w;
    s *= scale;
    s = inval[lk] != 0.f ? -1e9f : s;
    float p = expf(s - m);
    denom += p;
    float4 va = vs4[lk * 2], vb = vs4[lk * 2 + 1];
    o0.x += p * va.x; o0.y += p * va.y; o0.z += p * va.z; o0.w += p * va.w;
    o1.x += p * vb.x; o1.y += p * vb.y; o1.z += p * vb.z; o1.w += p * vb.w;
  }
  float inv = 1.f / denom;
  float4* a4 = (float4*)attno;
  long ob = ((long)b * 512 + lq) * 8 + h * 2;
  a4[ob]     = make_float4(o0.x*inv, o0.y*inv, o0.z*inv, o0.w*inv);
  a4[ob + 1] = make_float4(o1.x*inv, o1.y*inv, o1.z*inv, o1.w*inv);
}

// ---------------- K3: x = LN1(x + attno @ Wout.T + bout)  (per-token) ----------------
__global__ __launch_bounds__(64) void k_oproj_ln(const float* __restrict__ attno,
                                                 const float* __restrict__ W,
                                                 const float* __restrict__ b,
                                                 const float* __restrict__ g,
                                                 const float* __restrict__ beta,
                                                 float* __restrict__ x) {
  long token = (long)blockIdx.x * 64 + threadIdx.x;
  const float4* a4 = (const float4*)attno;
  const float4* x4 = (const float4*)x;
  const float4* W4 = (const float4*)W;
  float4 orow[8];
  float xr[32];
  #pragma unroll
  for (int j4 = 0; j4 < 8; j4++) {
    orow[j4] = a4[token * 8 + j4];
    float4 v = x4[token * 8 + j4];
    xr[j4*4] = v.x; xr[j4*4+1] = v.y; xr[j4*4+2] = v.z; xr[j4*4+3] = v.w;
  }
  float v[32];
  #pragma unroll
  for (int c = 0; c < 32; c++) {
    float acc = 0.f;
    #pragma unroll
    for (int j4 = 0; j4 < 8; j4++) {
      float4 wv = W4[c * 8 + j4];   // uniform
      acc += orow[j4].x * wv.x + orow[j4].y * wv.y + orow[j4].z * wv.z + orow[j4].w * wv.w;
    }
    v[c] = acc + b[c] + xr[c];
  }
  float mu = 0.f;
  #pragma unroll
  for (int c = 0; c < 32; c++) mu += v[c];
  mu *= 0.03125f;
  float var = 0.f;
  #pragma unroll
  for (int c = 0; c < 32; c++) { float d = v[c] - mu; var += d * d; }
  var *= 0.03125f;
  float inv = 1.f / sqrtf(var + 1e-5f);
  float4* xo4 = (float4*)x;
  #pragma unroll
  for (int j4 = 0; j4 < 8; j4++) {
    float4 o;
    o.x = g[j4*4]   * (v[j4*4]   - mu) * inv + beta[j4*4];
    o.y = g[j4*4+1] * (v[j4*4+1] - mu) * inv + beta[j4*4+1];
    o.z = g[j4*4+2] * (v[j4*4+2] - mu) * inv + beta[j4*4+2];
    o.w = g[j4*4+3] * (v[j4*4+3] - mu) * inv + beta[j4*4+3];
    xo4[token * 8 + j4] = o;
  }
}

// ---------------- K4: x = LN2(x + relu(x@W1.T+b1)@W2.T + b2)  (per-token) ----------------
__global__ __launch_bounds__(64) void k_ffn_ln(const float* __restrict__ x,
                                               const float* __restrict__ W1,
                                               const float* __restrict__ b1,
                                               const float* __restrict__ W2,
                                               const float* __restrict__ b2,
                                               const float* __restrict__ g,
                                               const float* __restrict__ beta,
                                               float* __restrict__ xout) {
  long token = (long)blockIdx.x * 64 + threadIdx.x;
  const float4* x4 = (const float4*)x;
  const float4* W14 = (const float4*)W1;
  const float4* W24 = (const float4*)W2;
  float xr[32];
  #pragma unroll
  for (int j4 = 0; j4 < 8; j4++) {
    float4 v = x4[token * 8 + j4];
    xr[j4*4] = v.x; xr[j4*4+1] = v.y; xr[j4*4+2] = v.z; xr[j4*4+3] = v.w;
  }
  float h[64];
  #pragma unroll
  for (int c = 0; c < 64; c++) {
    float acc = 0.f;
    #pragma unroll
    for (int j4 = 0; j4 < 8; j4++) {
      float4 wv = W14[c * 8 + j4];   // uniform
      acc += xr[j4*4] * wv.x + xr[j4*4+1] * wv.y + xr[j4*4+2] * wv.z + xr[j4*4+3] * wv.w;
    }
    h[c] = fmaxf(acc + b1[c], 0.f);
  }
  float v[32];
  #pragma unroll
  for (int c = 0; c < 32; c++) {
    float acc = 0.f;
    #pragma unroll
    for (int j4 = 0; j4 < 16; j4++) {
      float4 wv = W24[c * 16 + j4];   // uniform
      acc += h[j4*4] * wv.x + h[j4*4+1] * wv.y + h[j4*4+2] * wv.z + h[j4*4+3] * wv.w;
    }
    v[c] = acc + b2[c] + xr[c];
  }
  float mu = 0.f;
  #pragma unroll
  for (int c = 0; c < 32; c++) mu += v[c];
  mu *= 0.03125f;
  float var = 0.f;
  #pragma unroll
  for (int c = 0; c < 32; c++) { float d = v[c] - mu; var += d * d; }
  var *= 0.03125f;
  float inv = 1.f / sqrtf(var + 1e-5f);
  float4* xo4 = (float4*)xout;
  #pragma unroll
  for (int j4 = 0; j4 < 8; j4++) {
    float4 o;
    o.x = g[j4*4]   * (v[j4*4]   - mu) * inv + beta[j4*4];
    o.y = g[j4*4+1] * (v[j4*4+1] - mu) * inv + beta[j4*4+1];
    o.z = g[j4*4+2] * (v[j4*4+2] - mu) * inv + beta[j4*4+2];
    o.w = g[j4*4+3] * (v[j4*4+3] - mu) * inv + beta[j4*4+3];
    xo4[token * 8 + j4] = o;
  }
}

// ---------------- K5: flat = x[:, :16] @ fc_out_w.T + b  (one batch per block) ----------
__global__ __launch_bounds__(256) void k_fcout(const float* __restrict__ x,
                                               const float* __restrict__ W,
                                               const float* __restrict__ b,
                                               float* __restrict__ flat) {
  int bb = blockIdx.x;    // 0..63
  __shared__ float xs[16 * 32];
  int t = threadIdx.x;
  if (t < 128) {
    int row = t >> 3, j4 = t & 7;
    *(float4*)(xs + row * 32 + j4 * 4) =
        *(const float4*)(x + ((long)bb * 512 + row) * 32 + j4 * 4);
  }
  __syncthreads();
  #pragma unroll
  for (int i = 0; i < 3; i++) {
    int e = t + 256 * i;
    const float4* w4 = (const float4*)(W + e * 32);
    float4 wv[8];
    #pragma unroll
    for (int j4 = 0; j4 < 8; j4++) wv[j4] = w4[j4];
    float bias = b[e];
    #pragma unroll
    for (int r = 0; r < 16; r++) {
      float s = 0.f;
      #pragma unroll
      for (int j4 = 0; j4 < 8; j4++) {
        const float* xr = xs + r * 32 + j4 * 4;
        s += xr[0] * wv[j4].x + xr[1] * wv[j4].y + xr[2] * wv[j4].z + xr[3] * wv[j4].w;
      }
      flat[((long)bb * 16 + r) * 768 + e] = s + bias;
    }
  }
}

// ---------------- K6: cb_sq[k] = sum(codebook[k]^2) ----------------
__global__ __launch_bounds__(256) void k_cbsq(const float* __restrict__ cb,
                                              float* __restrict__ cb_sq) {
  int w = threadIdx.x >> 6, lane = threadIdx.x & 63;
  int k = blockIdx.x * 4 + w;
  const float* row = cb + (long)k * 768;
  float s = 0.f;
  #pragma unroll
  for (int i = 0; i < 12; i++) { float v = row[lane + 64 * i]; s += v * v; }
  #pragma unroll
  for (int off = 32; off >= 1; off >>= 1) s += __shfl_xor(s, off);
  if (lane == 0) cb_sq[k] = s;
}

// ---------------- K7: logits[n,k] = 2*dot - csq[k] - 1e-5  (row-constant fsq dropped;
//                  gumbel-max is invariant to per-row shifts) ----------------
// 64 rows x 256 cols per block; thread: 8 rows x 8 cols (cols strided by 32).
__global__ __launch_bounds__(256, 2) void k_logits(const float* __restrict__ flat,
                                                   const float* __restrict__ cb,
                                                   const float* __restrict__ cb_sq,
                                                   float* __restrict__ logits) {
  int rb = blockIdx.x >> 5;      // 0..15
  int cblk = blockIdx.x & 31;    // 0..31
  __shared__ float fs[64 * 36];  // 9 KB
  __shared__ float cs[256 * 36]; // 36 KB
  int t = threadIdx.x;
  int r0 = (t >> 5) * 8;         // rows r0..r0+8 (2 distinct per wave -> broadcast reads)
  int c0 = t & 31;               // cols c0 + 32*ci (consecutive lanes -> distinct banks)
  long frow = (long)rb * 64;
  long cbase = (long)cblk * 256;
  float acc[8][8];
  #pragma unroll
  for (int ri = 0; ri < 8; ri++)
    #pragma unroll
    for (int ci = 0; ci < 8; ci++) acc[ri][ci] = 0.f;

  for (int kc = 0; kc < 768; kc += 32) {
    __syncthreads();
    #pragma unroll
    for (int p = 0; p < 2; p++) {
      int f = t + 256 * p;
      int row = f >> 3, k4 = f & 7;
      *(float4*)(fs + row * 36 + k4 * 4) =
          *(const float4*)(flat + (frow + row) * 768 + kc + k4 * 4);
    }
    #pragma unroll
    for (int p = 0; p < 8; p++) {
      int col = p * 32 + (t >> 3), k4 = t & 7;
      *(float4*)(cs + col * 36 + k4 * 4) =
          *(const float4*)(cb + (cbase + col) * 768 + kc + k4 * 4);
    }
    __syncthreads();
    #pragma unroll
    for (int k4 = 0; k4 < 8; k4++) {
      float4 fa[8], fb[8];
      #pragma unroll
      for (int i = 0; i < 8; i++) fa[i] = *(const float4*)(fs + (r0 + i) * 36 + k4 * 4);
      #pragma unroll
      for (int i = 0; i < 8; i++) fb[i] = *(const float4*)(cs + (c0 + 32 * i) * 36 + k4 * 4);
      #pragma unroll
      for (int ri = 0; ri < 8; ri++) {
        #pragma unroll
        for (int ci = 0; ci < 8; ci++) {
          acc[ri][ci] = fmaf(fa[ri].x, fb[ci].x, acc[ri][ci]);
          acc[ri][ci] = fmaf(fa[ri].y, fb[ci].y, acc[ri][ci]);
          acc[ri][ci] = fmaf(fa[ri].z, fb[ci].z, acc[ri][ci]);
          acc[ri][ci] = fmaf(fa[ri].w, fb[ci].w, acc[ri][ci]);
        }
      }
    }
  }
  #pragma unroll
  for (int ci = 0; ci < 8; ci++) {
    long col = cbase + c0 + 32 * ci;
    float csq = cb_sq[col];
    #pragma unroll
    for (int ri = 0; ri < 8; ri++) {
      long n = frow + r0 + ri;
      logits[n * 8192 + col] = 2.f * acc[ri][ci] - csq - 1e-5f;
    }
  }
}

// ---------------- K8: 16 gumbel-max draws per row -> xq -> output 0 ----------------
__global__ __launch_bounds__(256) void k_sample(const float* __restrict__ logits,
                                                const float* __restrict__ cb,
                                                const float* __restrict__ flat,
                                                float* __restrict__ out0) {
  int n = blockIdx.x, t = threadIdx.x;
  const float* lrow = logits + (long)n * 8192;
  __shared__ float s_max[4];
  __shared__ int s_cnt;
  __shared__ int cand[8192];
  __shared__ float redv[64];
  __shared__ int redi[64];
  __shared__ int draws[16];
  float m = -3.4e38f;
  for (int i = 0; i < 32; i++) m = fmaxf(m, lrow[t + 256 * i]);
  #pragma unroll
  for (int off = 32; off >= 1; off >>= 1) m = fmaxf(m, __shfl_xor(m, off));
  if ((t & 63) == 0) s_max[t >> 6] = m;
  if (t == 0) s_cnt = 0;
  __syncthreads();
  float rowmax = fmaxf(fmaxf(s_max[0], s_max[1]), fmaxf(s_max[2], s_max[3]));
  float thresh = rowmax - 20.5f;   // gumbel range is [-4.47, 15.95]
  for (int i = 0; i < 32; i++) {
    int k = t + 256 * i;
    if (lrow[k] >= thresh) { int p = atomicAdd(&s_cnt, 1); cand[p] = k; }
  }
  __syncthreads();
  int ncand = s_cnt;
  float bv[16]; int bi[16];
  #pragma unroll
  for (int s = 0; s < 16; s++) { bv[s] = -3.4e38f; bi[s] = 0x7fffffff; }
  for (int c = t; c < ncand; c += 256) {
    int k = cand[c];
    float lg = lrow[k];
    #pragma unroll
    for (int s = 0; s < 16; s++) {
      uint32_t idx = ((uint32_t)((s << 10) + n) << 13) | (uint32_t)k;
      float val = gumbel_at(idx) + lg;
      if (val > bv[s] || (val == bv[s] && k < bi[s])) { bv[s] = val; bi[s] = k; }
    }
  }
  #pragma unroll
  for (int s = 0; s < 16; s++) {
    #pragma unroll
    for (int off = 32; off >= 1; off >>= 1) {
      float ov = __shfl_xor(bv[s], off);
      int oi = __shfl_xor(bi[s], off);
      if (ov > bv[s] || (ov == bv[s] && oi < bi[s])) { bv[s] = ov; bi[s] = oi; }
    }
    if ((t & 63) == 0) { redv[s * 4 + (t >> 6)] = bv[s]; redi[s * 4 + (t >> 6)] = bi[s]; }
  }
  __syncthreads();
  if (t < 16) {
    float bvv = redv[t * 4]; int bii = redi[t * 4];
    #pragma unroll
    for (int w = 1; w < 4; w++) {
      float ov = redv[t * 4 + w]; int oi = redi[t * 4 + w];
      if (ov > bvv || (ov == bvv && oi < bii)) { bvv = ov; bii = oi; }
    }
    draws[t] = bii;
  }
  __syncthreads();
  #pragma unroll
  for (int i = 0; i < 3; i++) {
    int e = t + 256 * i;
    float ssum = 0.f;
    #pragma unroll
    for (int s = 0; s < 16; s++) ssum += cb[(long)draws[s] * 768 + e];
    float xq = ssum * 0.0625f;
    float fl = flat[(long)n * 768 + e];
    out0[(long)n * 768 + e] = fl + (xq - fl);
  }
}

extern "C" void kernel_launch(void* const* d_in, const int* in_sizes, int n_in,
                              void* d_out, int out_size, void* d_ws, size_t ws_size,
                              hipStream_t stream) {
  (void)in_sizes; (void)n_in; (void)out_size; (void)ws_size;
  const float* xcq      = (const float*)d_in[0];
  const int*   amask    = (const int*)d_in[1];
  const float* fc_in_w  = (const float*)d_in[2];
  const float* fc_in_b  = (const float*)d_in[3];
  const float* fc_out_w = (const float*)d_in[4];
  const float* fc_out_b = (const float*)d_in[5];
  const float* enc_in_w = (const float*)d_in[6];
  const float* enc_in_b = (const float*)d_in[7];
  const float* enc_out_w= (const float*)d_in[8];
  const float* enc_out_b= (const float*)d_in[9];
  const float* ff1w     = (const float*)d_in[10];
  const float* ff1b     = (const float*)d_in[11];
  const float* ff2w     = (const float*)d_in[12];
  const float* ff2b     = (const float*)d_in[13];
  const float* ln1g     = (const float*)d_in[14];
  const float* ln1b     = (const float*)d_in[15];
  const float* ln2g     = (const float*)d_in[16];
  const float* ln2b     = (const float*)d_in[17];
  const float* cb       = (const float*)d_in[18];
  float* out = (float*)d_out;
  float* ws  = (float*)d_ws;

  float* x      = ws + OFF_X;
  float* qkv    = ws + OFF_QKV;
  float* attno  = ws + OFF_ATTN;
  float* flat   = ws + OFF_FLAT;
  float* csq    = ws + OFF_CSQ;
  float* logits = ws + OFF_LOGITS;

  k_fcin<<<512, 256, 0, stream>>>(xcq, fc_in_w, fc_in_b, x, out + 786432);
  for (int l = 0; l < 2; l++) {
    k_qkv<<<512, 64, 0, stream>>>(x, enc_in_w + l * 96 * 32, enc_in_b + l * 96, qkv);
    k_attn<<<512, 256, 0, stream>>>(qkv, amask, attno);
    k_oproj_ln<<<512, 64, 0, stream>>>(attno, enc_out_w + l * 32 * 32, enc_out_b + l * 32,
                                       ln1g + l * 32, ln1b + l * 32, x);
    k_ffn_ln<<<512, 64, 0, stream>>>(x, ff1w + l * 64 * 32, ff1b + l * 64,
                                     ff2w + l * 32 * 64, ff2b + l * 32,
                                     ln2g + l * 32, ln2b + l * 32, x);
  }
  k_fcout<<<64, 256, 0, stream>>>(x, fc_out_w, fc_out_b, flat);
  k_cbsq<<<2048, 256, 0, stream>>>(cb, csq);
  k_logits<<<512, 256, 0, stream>>>(flat, cb, csq, logits);
  k_sample<<<1024, 256, 0, stream>>>(logits, cb, flat, out);
}